// Round 3
// baseline (237.034 us; speedup 1.0000x reference)
//
#include <hip/hip_runtime.h>
#include <hip/hip_bf16.h>
#include <cmath>

#define BB 2
#define TT 64
#define CC 384
#define HH 768

// d_out flat offsets (fp32 elements): out, nW0, nb0, nW1, nb1
#define O_OUT 0
#define O_NW0 768
#define O_NB0 (768 + 589824)
#define O_NW1 (O_NB0 + 1536)
#define O_NB1 (O_NW1 + 589824)

struct Coefs { float ct[TT]; float dfac; };

// K1: k = x@Wk^T+bk, v = x@Wv^T+bv  (blocks 0..127, one per (b,t));
//     q = iq@Wq^T+bq (block 128). 384 threads, one output channel each.
__global__ void k_qkv(const float* __restrict__ x,
                      const float* __restrict__ Wq, const float* __restrict__ bq,
                      const float* __restrict__ Wk, const float* __restrict__ bk,
                      const float* __restrict__ Wv, const float* __restrict__ bv,
                      const float* __restrict__ iq,
                      float* __restrict__ kb, float* __restrict__ vb, float* __restrict__ qb) {
    __shared__ float xs[CC];
    const int blk = blockIdx.x, j = threadIdx.x;
    if (blk < BB * TT) {
        xs[j] = x[(size_t)blk * CC + j];
        __syncthreads();
        float acck = bk[j], accv = bv[j];
        const float4* wk = (const float4*)(Wk + (size_t)j * CC);
        const float4* wv = (const float4*)(Wv + (size_t)j * CC);
        for (int i = 0; i < CC / 4; ++i) {
            float4 a = wk[i], b = wv[i];
            float x0 = xs[i * 4], x1 = xs[i * 4 + 1], x2 = xs[i * 4 + 2], x3 = xs[i * 4 + 3];
            acck += x0 * a.x + x1 * a.y + x2 * a.z + x3 * a.w;
            accv += x0 * b.x + x1 * b.y + x2 * b.z + x3 * b.w;
        }
        kb[(size_t)blk * CC + j] = acck;
        vb[(size_t)blk * CC + j] = accv;
    } else {
        xs[j] = iq[j];
        __syncthreads();
        float acc = bq[j];
        const float4* w = (const float4*)(Wq + (size_t)j * CC);
        for (int i = 0; i < CC / 4; ++i) {
            float4 a = w[i];
            acc += xs[i * 4] * a.x + xs[i * 4 + 1] * a.y + xs[i * 4 + 2] * a.z + xs[i * 4 + 3] * a.w;
        }
        qb[j] = acc;
    }
}

// K2: h1_pre[b,t,h] = k[b,t,:]·sW0[b,h,:] + sb0  -> h1 (silu) and dsilu factor.
// Blocks 0..127 tokens; 128..129 retrieval rows (use q). 256 threads x 3 h each.
__global__ void k_h1(const float* __restrict__ kb, const float* __restrict__ qb,
                     const float* __restrict__ sW0, const float* __restrict__ sb0,
                     float* __restrict__ h1, float* __restrict__ dsil, float* __restrict__ hret) {
    __shared__ float row[CC];
    const int blk = blockIdx.x, j = threadIdx.x;
    int b; const float* src; bool ret;
    if (blk < BB * TT) { b = blk / TT; src = kb + (size_t)blk * CC; ret = false; }
    else               { b = blk - BB * TT; src = qb; ret = true; }
    for (int i = j; i < CC; i += 256) row[i] = src[i];
    __syncthreads();
    for (int r = 0; r < 3; ++r) {
        int hh = j + r * 256;
        float acc = sb0[b * HH + hh];
        const float4* w = (const float4*)(sW0 + ((size_t)b * HH + hh) * CC);
        for (int i = 0; i < CC / 4; ++i) {
            float4 a = w[i];
            acc += row[i * 4] * a.x + row[i * 4 + 1] * a.y + row[i * 4 + 2] * a.z + row[i * 4 + 3] * a.w;
        }
        float sig = 1.f / (1.f + expf(-acc));
        float hv = acc * sig;
        if (!ret) {
            h1[(size_t)blk * HH + hh] = hv;
            dsil[(size_t)blk * HH + hh] = sig * (1.f + acc * (1.f - sig));
        } else {
            hret[b * HH + hh] = hv;
        }
    }
}

// K3: p[b,t,c] = h1[b,t,:]·sW1[b,c,:] + sb1; dp = p - v. Retrieval: pred.
// Blocks 0..127 tokens; 128..129 retrieval. 384 threads, one c each.
__global__ void k_p(const float* __restrict__ h1, const float* __restrict__ hret,
                    const float* __restrict__ vb,
                    const float* __restrict__ sW1, const float* __restrict__ sb1,
                    float* __restrict__ dp, float* __restrict__ pred) {
    __shared__ float row[HH];
    const int blk = blockIdx.x, j = threadIdx.x;
    int b; const float* src; bool ret;
    if (blk < BB * TT) { b = blk / TT; src = h1 + (size_t)blk * HH; ret = false; }
    else               { b = blk - BB * TT; src = hret + (size_t)b * HH; ret = true; }
    for (int i = j; i < HH; i += 384) row[i] = src[i];
    __syncthreads();
    float acc = sb1[b * CC + j];
    const float4* w = (const float4*)(sW1 + ((size_t)b * CC + j) * HH);
    for (int i = 0; i < HH / 4; ++i) {
        float4 a = w[i];
        acc += row[i * 4] * a.x + row[i * 4 + 1] * a.y + row[i * 4 + 2] * a.z + row[i * 4 + 3] * a.w;
    }
    if (!ret) dp[(size_t)blk * CC + j] = acc - vb[(size_t)blk * CC + j];
    else      pred[b * CC + j] = acc;
}

// K4: dh1[b,t,h] = sum_c dp[b,t,c]*sW1[b,c,h]; dh1p = dh1 * dsil.
// Blocks 0..127 (b,t); 256 threads x 3 h. sW1 column reads are coalesced across lanes.
__global__ void k_dh1(const float* __restrict__ dp, const float* __restrict__ dsil,
                      const float* __restrict__ sW1, float* __restrict__ dh1p) {
    __shared__ float row[CC];
    const int blk = blockIdx.x, j = threadIdx.x;
    const int b = blk / TT;
    for (int i = j; i < CC; i += 256) row[i] = dp[(size_t)blk * CC + i];
    __syncthreads();
    for (int r = 0; r < 3; ++r) {
        int hh = j + r * 256;
        const float* col = sW1 + (size_t)b * CC * HH + hh;
        float acc = 0.f;
        for (int c = 0; c < CC; ++c) acc += row[c] * col[(size_t)c * HH];
        dh1p[(size_t)blk * HH + hh] = acc * dsil[(size_t)blk * HH + hh];
    }
}

// K5: role-dispatched epilogue.
//  blocks [0,288):   nW1[b,c,h] = dfac*sW1 - sum_t (ct[t]*dp[b,t,c])*h1[b,t,h]   tiles 32c x 64h
//  blocks [288,576): nW0[b,h,c] = dfac*sW0 - sum_t (ct[t]*dh1p[b,t,h])*k[b,t,c]  tiles 32h x 64c
//  blocks [576,578): out[b,:] = pred[b,:]@Wo^T + bo
//  blocks [578,580): nb1, nb0
__global__ void k_epi(const float* __restrict__ dp, const float* __restrict__ h1,
                      const float* __restrict__ dh1p, const float* __restrict__ kb,
                      const float* __restrict__ pred,
                      const float* __restrict__ sW0, const float* __restrict__ sb0,
                      const float* __restrict__ sW1, const float* __restrict__ sb1,
                      const float* __restrict__ Wo, const float* __restrict__ bo,
                      float* __restrict__ out, Coefs cf) {
    __shared__ float a_t[TT][32];
    __shared__ float e_t[TT][64];
    __shared__ float pr[CC];
    const int blk = blockIdx.x, j = threadIdx.x;

    if (blk < 288) {                       // nW1
        const int b = blk / 144, rem = blk % 144;
        const int c0 = (rem / 12) * 32, h0 = (rem % 12) * 64;
        for (int i = j; i < TT * 32; i += 256) {
            int t = i >> 5, c = i & 31;
            a_t[t][c] = cf.ct[t] * dp[((size_t)(b * TT + t)) * CC + c0 + c];
        }
        for (int i = j; i < TT * 64; i += 256) {
            int t = i >> 6, h = i & 63;
            e_t[t][h] = h1[((size_t)(b * TT + t)) * HH + h0 + h];
        }
        __syncthreads();
        const int ci = j & 31, hb = (j >> 5) * 8;
        float acc[8] = {0, 0, 0, 0, 0, 0, 0, 0};
        for (int t = 0; t < TT; ++t) {
            float av = a_t[t][ci];
            #pragma unroll
            for (int m = 0; m < 8; ++m) acc[m] += av * e_t[t][hb + m];
        }
        const size_t idx = ((size_t)b * CC + c0 + ci) * HH + h0 + hb;
        const float4* w4 = (const float4*)(sW1 + idx);
        float4 wa = w4[0], wb = w4[1];
        float4 o0, o1;
        o0.x = cf.dfac * wa.x - acc[0]; o0.y = cf.dfac * wa.y - acc[1];
        o0.z = cf.dfac * wa.z - acc[2]; o0.w = cf.dfac * wa.w - acc[3];
        o1.x = cf.dfac * wb.x - acc[4]; o1.y = cf.dfac * wb.y - acc[5];
        o1.z = cf.dfac * wb.z - acc[6]; o1.w = cf.dfac * wb.w - acc[7];
        *(float4*)(out + O_NW1 + idx) = o0;
        *(float4*)(out + O_NW1 + idx + 4) = o1;
    } else if (blk < 576) {                // nW0
        const int bk2 = blk - 288;
        const int b = bk2 / 144, rem = bk2 % 144;
        const int h0 = (rem / 6) * 32, c0 = (rem % 6) * 64;
        for (int i = j; i < TT * 32; i += 256) {
            int t = i >> 5, h = i & 31;
            a_t[t][h] = cf.ct[t] * dh1p[((size_t)(b * TT + t)) * HH + h0 + h];
        }
        for (int i = j; i < TT * 64; i += 256) {
            int t = i >> 6, c = i & 63;
            e_t[t][c] = kb[((size_t)(b * TT + t)) * CC + c0 + c];
        }
        __syncthreads();
        const int hi = j & 31, cb = (j >> 5) * 8;
        float acc[8] = {0, 0, 0, 0, 0, 0, 0, 0};
        for (int t = 0; t < TT; ++t) {
            float av = a_t[t][hi];
            #pragma unroll
            for (int m = 0; m < 8; ++m) acc[m] += av * e_t[t][cb + m];
        }
        const size_t idx = ((size_t)b * HH + h0 + hi) * CC + c0 + cb;
        const float4* w4 = (const float4*)(sW0 + idx);
        float4 wa = w4[0], wb = w4[1];
        float4 o0, o1;
        o0.x = cf.dfac * wa.x - acc[0]; o0.y = cf.dfac * wa.y - acc[1];
        o0.z = cf.dfac * wa.z - acc[2]; o0.w = cf.dfac * wa.w - acc[3];
        o1.x = cf.dfac * wb.x - acc[4]; o1.y = cf.dfac * wb.y - acc[5];
        o1.z = cf.dfac * wb.z - acc[6]; o1.w = cf.dfac * wb.w - acc[7];
        *(float4*)(out + O_NW0 + idx) = o0;
        *(float4*)(out + O_NW0 + idx + 4) = o1;
    } else if (blk < 578) {                // out = pred@Wo^T + bo
        const int b = blk - 576;
        for (int i = j; i < CC; i += 256) pr[i] = pred[b * CC + i];
        __syncthreads();
        for (int c = j; c < CC; c += 256) {
            float acc = bo[c];
            const float4* w = (const float4*)(Wo + (size_t)c * CC);
            for (int i = 0; i < CC / 4; ++i) {
                float4 a = w[i];
                acc += pr[i * 4] * a.x + pr[i * 4 + 1] * a.y + pr[i * 4 + 2] * a.z + pr[i * 4 + 3] * a.w;
            }
            out[O_OUT + b * CC + c] = acc;
        }
    } else {                               // nb1, nb0
        const int b = blk - 578;
        for (int c = j; c < CC; c += 256) {
            float acc = 0.f;
            for (int t = 0; t < TT; ++t) acc += cf.ct[t] * dp[((size_t)(b * TT + t)) * CC + c];
            out[O_NB1 + b * CC + c] = cf.dfac * sb1[b * CC + c] - acc;
        }
        for (int h = j; h < HH; h += 256) {
            float acc = 0.f;
            for (int t = 0; t < TT; ++t) acc += cf.ct[t] * dh1p[((size_t)(b * TT + t)) * HH + h];
            out[O_NB0 + b * HH + h] = cf.dfac * sb0[b * HH + h] - acc;
        }
    }
}

extern "C" void kernel_launch(void* const* d_in, const int* in_sizes, int n_in,
                              void* d_out, int out_size, void* d_ws, size_t ws_size,
                              hipStream_t stream) {
    const float* x   = (const float*)d_in[0];
    const float* Wq  = (const float*)d_in[1];
    const float* bq  = (const float*)d_in[2];
    const float* Wk  = (const float*)d_in[3];
    const float* bk  = (const float*)d_in[4];
    const float* Wv  = (const float*)d_in[5];
    const float* bv  = (const float*)d_in[6];
    const float* Wo  = (const float*)d_in[7];
    const float* bo  = (const float*)d_in[8];
    const float* iq  = (const float*)d_in[9];
    const float* sW0 = (const float*)d_in[10];
    const float* sb0 = (const float*)d_in[11];
    const float* sW1 = (const float*)d_in[12];
    const float* sb1 = (const float*)d_in[13];

    float* ws   = (float*)d_ws;
    float* kb   = ws;                    // 49152
    float* vb   = kb + 49152;            // 49152
    float* qb   = vb + 49152;            // 384
    float* h1   = qb + 384;              // 98304
    float* dsil = h1 + 98304;            // 98304
    float* hret = dsil + 98304;          // 1536
    float* dp   = hret + 1536;           // 49152
    float* pred = dp + 49152;            // 768
    float* dh1p = pred + 768;            // 98304  -> total ~1.78 MB

    // Closed-form scan coefficients (exact: the clipped seed gate cancels).
    Coefs cf;
    const double mom = 0.9, decay = 1.0 - 0.001, lr = 0.01;
    for (int s = 0; s < TT; ++s) {
        double sum = 0.0;
        for (int t = s; t < TT; ++t) sum += pow(decay, (double)(TT - 1 - t)) * pow(mom, (double)(t - s));
        cf.ct[s] = (float)(lr * (1.0 - mom) * sum);
    }
    cf.dfac = (float)pow(decay, (double)TT);

    k_qkv<<<dim3(BB * TT + 1), dim3(CC), 0, stream>>>(x, Wq, bq, Wk, bk, Wv, bv, iq, kb, vb, qb);
    k_h1 <<<dim3(BB * TT + BB), dim3(256), 0, stream>>>(kb, qb, sW0, sb0, h1, dsil, hret);
    k_p  <<<dim3(BB * TT + BB), dim3(CC), 0, stream>>>(h1, hret, vb, sW1, sb1, dp, pred);
    k_dh1<<<dim3(BB * TT), dim3(256), 0, stream>>>(dp, dsil, sW1, dh1p);
    k_epi<<<dim3(580), dim3(256), 0, stream>>>(dp, h1, dh1p, kb, pred, sW0, sb0, sW1, sb1, Wo, bo,
                                               (float*)d_out, cf);
}

// Round 5
// 144.645 us; speedup vs baseline: 1.6387x; 1.6387x over previous
//
#include <hip/hip_runtime.h>
#include <hip/hip_bf16.h>
#include <cmath>

#define BB 2
#define TT 64
#define CC 384
#define HH 768

// d_out flat offsets (fp32 elements): out, nW0, nb0, nW1, nb1
#define O_OUT 0
#define O_NW0 768
#define O_NB0 (768 + 589824)
#define O_NW1 (O_NB0 + 1536)
#define O_NB1 (O_NW1 + 589824)

struct Coefs { float ct[TT]; float dfac; };

typedef __attribute__((ext_vector_type(8))) short bf16x8;
typedef __attribute__((ext_vector_type(4))) float f32x4;

__device__ __forceinline__ float bf2f(unsigned short u) {
    union { unsigned int i; float f; } x; x.i = ((unsigned int)u) << 16; return x.f;
}
__device__ __forceinline__ unsigned short f2bf(float f) {
    union { float f; unsigned int i; } u; u.f = f;
    unsigned int x = u.i;
    unsigned int r = (x + 0x7fffu + ((x >> 16) & 1u)) >> 16;  // RNE
    return (unsigned short)r;
}
__device__ __forceinline__ f32x4 mfma16(bf16x8 a, bf16x8 b, f32x4 c) {
    return __builtin_amdgcn_mfma_f32_16x16x32_bf16(a, b, c, 0, 0, 0);
}
__device__ __forceinline__ bf16x8 ldbf8(const unsigned short* p) {
    return *(const bf16x8*)p;
}

// ---------------- conversion kernel: fp32 -> bf16 copies (+ sW1 transpose) ----------------
// blocks [0,1776): flat convert (float4 granularity)
// blocks [1776, 1776+576): sW1T[b][h][c] = bf16(sW1[b][c][h]), 32x32 LDS tiles,
//                          256 threads x 4 rows each.
__global__ void k_conv(const float* __restrict__ x,  const float* __restrict__ Wq,
                       const float* __restrict__ Wk, const float* __restrict__ Wv,
                       const float* __restrict__ Wo, const float* __restrict__ sW0,
                       const float* __restrict__ sW1,
                       unsigned short* __restrict__ x_bf,  unsigned short* __restrict__ Wq_bf,
                       unsigned short* __restrict__ Wk_bf, unsigned short* __restrict__ Wv_bf,
                       unsigned short* __restrict__ Wo_bf, unsigned short* __restrict__ sW0_bf,
                       unsigned short* __restrict__ sW1_bf, unsigned short* __restrict__ sW1T_bf) {
    const int blk = blockIdx.x, j = threadIdx.x;
    if (blk < 1776) {
        int g = blk * 256 + j;   // float4 index, total 454656
        const float* src; unsigned short* dst; int off;
        if      (g < 12288)  { src = x;   dst = x_bf;   off = g; }
        else if (g < 49152)  { src = Wq;  dst = Wq_bf;  off = g - 12288; }
        else if (g < 86016)  { src = Wk;  dst = Wk_bf;  off = g - 49152; }
        else if (g < 122880) { src = Wv;  dst = Wv_bf;  off = g - 86016; }
        else if (g < 159744) { src = Wo;  dst = Wo_bf;  off = g - 122880; }
        else if (g < 307200) { src = sW0; dst = sW0_bf; off = g - 159744; }
        else                 { src = sW1; dst = sW1_bf; off = g - 307200; }
        float4 v = ((const float4*)src)[off];
        ushort4 u;
        u.x = f2bf(v.x); u.y = f2bf(v.y); u.z = f2bf(v.z); u.w = f2bf(v.w);
        ((ushort4*)dst)[off] = u;
    } else {
        __shared__ float tile[32][33];
        const int r2 = blk - 1776;                 // [0,576)
        const int b = r2 / 288, rem = r2 % 288;
        const int c0 = (rem / 24) * 32, h0 = (rem % 24) * 32;
        const int row0 = j / 32, col = j % 32;     // row0 in [0,8)
        #pragma unroll
        for (int r = 0; r < 4; ++r) {
            int row = row0 + r * 8;
            tile[row][col] = sW1[((size_t)(b * CC + c0 + row)) * HH + h0 + col];
        }
        __syncthreads();
        #pragma unroll
        for (int r = 0; r < 4; ++r) {
            int row = row0 + r * 8;
            sW1T_bf[((size_t)(b * HH + h0 + row)) * CC + c0 + col] = f2bf(tile[col][row]);
        }
    }
}

// ---------------- K1: k|v via MFMA;  q via split GEMV ----------------
// blocks [0,24): MFMA. wave w = blk*4+wid in [0,96): mp=w%4 (m-pair of 8 m-frags),
//                np=w/4 (n-pair of 48 n-frags; n<384 -> Wk, else Wv)
// blocks [24,48): q GEMV: 16 outputs per block, 16-way K-split
__global__ void k_qkv(const unsigned short* __restrict__ x_bf,
                      const unsigned short* __restrict__ Wk_bf, const float* __restrict__ bk,
                      const unsigned short* __restrict__ Wv_bf, const float* __restrict__ bv,
                      const unsigned short* __restrict__ Wq_bf, const float* __restrict__ bq,
                      const float* __restrict__ iq,
                      unsigned short* __restrict__ kb_bf, float* __restrict__ vb,
                      float* __restrict__ qb) {
    __shared__ float vecs[CC];
    __shared__ float part[16][17];
    const int blk = blockIdx.x, j = threadIdx.x;
    if (blk < 24) {
        const int wid = j >> 6, L = j & 63;
        const int w = blk * 4 + wid;
        const int mp = w % 4, np = w / 4;
        const int lrow = L & 15, kq = (L >> 4) * 8;
        const unsigned short* A0 = x_bf + (size_t)(mp * 32 + lrow) * CC;
        const unsigned short* A1 = A0 + 16 * CC;
        const int n0 = (2 * np) * 16 + lrow, n1 = n0 + 16;
        const unsigned short* B0 = (n0 < CC) ? (Wk_bf + (size_t)n0 * CC) : (Wv_bf + (size_t)(n0 - CC) * CC);
        const unsigned short* B1 = (n1 < CC) ? (Wk_bf + (size_t)n1 * CC) : (Wv_bf + (size_t)(n1 - CC) * CC);
        f32x4 acc00 = {0,0,0,0}, acc01 = {0,0,0,0}, acc10 = {0,0,0,0}, acc11 = {0,0,0,0};
        for (int s = 0; s < CC / 32; ++s) {
            int k = s * 32 + kq;
            bf16x8 a0 = ldbf8(A0 + k), a1 = ldbf8(A1 + k);
            bf16x8 b0 = ldbf8(B0 + k), b1 = ldbf8(B1 + k);
            acc00 = mfma16(a0, b0, acc00); acc01 = mfma16(a0, b1, acc01);
            acc10 = mfma16(a1, b0, acc10); acc11 = mfma16(a1, b1, acc11);
        }
        const int quad = L >> 4;
        #pragma unroll
        for (int mi = 0; mi < 2; ++mi) {
            #pragma unroll
            for (int ni = 0; ni < 2; ++ni) {
                f32x4 acc = mi == 0 ? (ni == 0 ? acc00 : acc01) : (ni == 0 ? acc10 : acc11);
                int n = (2 * np + ni) * 16 + lrow;
                #pragma unroll
                for (int r = 0; r < 4; ++r) {
                    int m = mp * 32 + mi * 16 + quad * 4 + r;
                    float v = acc[r];
                    if (n < CC) kb_bf[(size_t)m * CC + n] = f2bf(v + bk[n]);
                    else        vb[(size_t)m * CC + (n - CC)] = v + bv[n - CC];
                }
            }
        }
    } else {
        // q = iq @ Wq^T + bq  (fp32 vec, bf16 weights)
        if (j < CC / 4) ((float4*)vecs)[j] = ((const float4*)iq)[j];
        __syncthreads();
        const int nt = blk - 24;
        const int nl = j & 15, ks = j >> 4;
        const int n = nt * 16 + nl;
        const unsigned short* wr = Wq_bf + (size_t)n * CC + ks * 24;
        float s = 0.f;
        for (int i = 0; i < 3; ++i) {
            bf16x8 wv8 = ldbf8(wr + i * 8);
            #pragma unroll
            for (int e = 0; e < 8; ++e)
                s += bf2f((unsigned short)wv8[e]) * vecs[ks * 24 + i * 8 + e];
        }
        part[ks][nl] = s;
        __syncthreads();
        if (j < 16) {
            float acc = bq[nt * 16 + j];
            #pragma unroll
            for (int kk = 0; kk < 16; ++kk) acc += part[kk][j];
            qb[nt * 16 + j] = acc;
        }
    }
}

// ---------------- K2: h1 = silu(kb @ sW0^T + sb0), dsil;  hret via GEMV ----------------
// blocks [0,24): MFMA per b (12 blocks each): w=(blk%12)*4+wid in [0,48): mp=w&1, np=w>>1
// blocks [24,120): hret GEMV: rb=blk-24: b=rb/48, nt=rb%48
__global__ void k_h1(const unsigned short* __restrict__ kb_bf, const float* __restrict__ qb,
                     const unsigned short* __restrict__ sW0_bf, const float* __restrict__ sb0,
                     unsigned short* __restrict__ h1_bf, float* __restrict__ dsil,
                     float* __restrict__ hret) {
    __shared__ float vecs[CC];
    __shared__ float part[16][17];
    const int blk = blockIdx.x, j = threadIdx.x;
    if (blk < 24) {
        const int b = blk / 12;
        const int wid = j >> 6, L = j & 63;
        const int w = (blk % 12) * 4 + wid;
        const int mp = w & 1, np = w >> 1;
        const int lrow = L & 15, kq = (L >> 4) * 8;
        const unsigned short* A0 = kb_bf + (size_t)(b * TT + mp * 32 + lrow) * CC;
        const unsigned short* A1 = A0 + 16 * CC;
        const int n0 = (2 * np) * 16 + lrow;
        const unsigned short* B0 = sW0_bf + (size_t)(b * HH + n0) * CC;
        const unsigned short* B1 = B0 + 16 * CC;
        f32x4 acc00 = {0,0,0,0}, acc01 = {0,0,0,0}, acc10 = {0,0,0,0}, acc11 = {0,0,0,0};
        for (int s = 0; s < CC / 32; ++s) {
            int k = s * 32 + kq;
            bf16x8 a0 = ldbf8(A0 + k), a1 = ldbf8(A1 + k);
            bf16x8 b0 = ldbf8(B0 + k), b1 = ldbf8(B1 + k);
            acc00 = mfma16(a0, b0, acc00); acc01 = mfma16(a0, b1, acc01);
            acc10 = mfma16(a1, b0, acc10); acc11 = mfma16(a1, b1, acc11);
        }
        const int quad = L >> 4;
        #pragma unroll
        for (int mi = 0; mi < 2; ++mi) {
            #pragma unroll
            for (int ni = 0; ni < 2; ++ni) {
                f32x4 acc = mi == 0 ? (ni == 0 ? acc00 : acc01) : (ni == 0 ? acc10 : acc11);
                int n = (2 * np + ni) * 16 + lrow;
                float bias = sb0[b * HH + n];
                #pragma unroll
                for (int r = 0; r < 4; ++r) {
                    int t = mp * 32 + mi * 16 + quad * 4 + r;
                    float pre = acc[r] + bias;
                    float sig = 1.f / (1.f + expf(-pre));
                    size_t idx = (size_t)(b * TT + t) * HH + n;
                    h1_bf[idx] = f2bf(pre * sig);
                    dsil[idx]  = sig * (1.f + pre * (1.f - sig));
                }
            }
        }
    } else {
        if (j < CC / 4) ((float4*)vecs)[j] = ((const float4*)qb)[j];
        __syncthreads();
        const int rb = blk - 24;
        const int b = rb / 48, nt = rb % 48;
        const int nl = j & 15, ks = j >> 4;
        const int n = nt * 16 + nl;
        const unsigned short* wr = sW0_bf + (size_t)(b * HH + n) * CC + ks * 24;
        float s = 0.f;
        for (int i = 0; i < 3; ++i) {
            bf16x8 wv8 = ldbf8(wr + i * 8);
            #pragma unroll
            for (int e = 0; e < 8; ++e)
                s += bf2f((unsigned short)wv8[e]) * vecs[ks * 24 + i * 8 + e];
        }
        part[ks][nl] = s;
        __syncthreads();
        if (j < 16) {
            int n2 = nt * 16 + j;
            float pre = sb0[b * HH + n2];
            #pragma unroll
            for (int kk = 0; kk < 16; ++kk) pre += part[kk][j];
            float sig = 1.f / (1.f + expf(-pre));
            hret[b * HH + n2] = pre * sig;
        }
    }
}

// ---------------- K3: dp = (h1 @ sW1^T + sb1) - v;  pred via GEMV ----------------
// blocks [0,12): MFMA per b (6 each): w=(blk%6)*4+wid in [0,24): mp=w&1, np=w>>1 (N=24 frags)
// blocks [12,60): pred GEMV: rb=blk-12: b=rb/24, nt=rb%24 (K=768)
__global__ void k_p(const unsigned short* __restrict__ h1_bf, const float* __restrict__ hret,
                    const float* __restrict__ vb,
                    const unsigned short* __restrict__ sW1_bf, const float* __restrict__ sb1,
                    unsigned short* __restrict__ dp_bf, float* __restrict__ pred) {
    __shared__ float vecs[HH];
    __shared__ float part[16][17];
    const int blk = blockIdx.x, j = threadIdx.x;
    if (blk < 12) {
        const int b = blk / 6;
        const int wid = j >> 6, L = j & 63;
        const int w = (blk % 6) * 4 + wid;
        const int mp = w & 1, np = w >> 1;
        const int lrow = L & 15, kq = (L >> 4) * 8;
        const unsigned short* A0 = h1_bf + (size_t)(b * TT + mp * 32 + lrow) * HH;
        const unsigned short* A1 = A0 + 16 * HH;
        const int n0 = (2 * np) * 16 + lrow;
        const unsigned short* B0 = sW1_bf + (size_t)(b * CC + n0) * HH;
        const unsigned short* B1 = B0 + 16 * HH;
        f32x4 acc00 = {0,0,0,0}, acc01 = {0,0,0,0}, acc10 = {0,0,0,0}, acc11 = {0,0,0,0};
        for (int s = 0; s < HH / 32; ++s) {
            int k = s * 32 + kq;
            bf16x8 a0 = ldbf8(A0 + k), a1 = ldbf8(A1 + k);
            bf16x8 b0 = ldbf8(B0 + k), b1 = ldbf8(B1 + k);
            acc00 = mfma16(a0, b0, acc00); acc01 = mfma16(a0, b1, acc01);
            acc10 = mfma16(a1, b0, acc10); acc11 = mfma16(a1, b1, acc11);
        }
        const int quad = L >> 4;
        #pragma unroll
        for (int mi = 0; mi < 2; ++mi) {
            #pragma unroll
            for (int ni = 0; ni < 2; ++ni) {
                f32x4 acc = mi == 0 ? (ni == 0 ? acc00 : acc01) : (ni == 0 ? acc10 : acc11);
                int n = (2 * np + ni) * 16 + lrow;
                float bias = sb1[b * CC + n];
                #pragma unroll
                for (int r = 0; r < 4; ++r) {
                    int t = mp * 32 + mi * 16 + quad * 4 + r;
                    size_t idx = (size_t)(b * TT + t) * CC + n;
                    dp_bf[idx] = f2bf(acc[r] + bias - vb[idx]);
                }
            }
        }
    } else {
        const int rb = blk - 12;
        const int b = rb / 24, nt = rb % 24;
        if (j < HH / 4) ((float4*)vecs)[j] = ((const float4*)(hret + b * HH))[j];
        __syncthreads();
        const int nl = j & 15, ks = j >> 4;
        const int n = nt * 16 + nl;
        const unsigned short* wr = sW1_bf + (size_t)(b * CC + n) * HH + ks * 48;
        float s = 0.f;
        for (int i = 0; i < 6; ++i) {
            bf16x8 wv8 = ldbf8(wr + i * 8);
            #pragma unroll
            for (int e = 0; e < 8; ++e)
                s += bf2f((unsigned short)wv8[e]) * vecs[ks * 48 + i * 8 + e];
        }
        part[ks][nl] = s;
        __syncthreads();
        if (j < 16) {
            int n2 = nt * 16 + j;
            float acc = sb1[b * CC + n2];
            #pragma unroll
            for (int kk = 0; kk < 16; ++kk) acc += part[kk][j];
            pred[b * CC + n2] = acc;
        }
    }
}

// ---------------- K4: dh1p = (dp @ sW1T^T) * dsil ----------------
// blocks [0,24): MFMA per b (12 each), same indexing as k_h1; B = sW1T (bf16, [b][h][c])
__global__ void k_dh1(const unsigned short* __restrict__ dp_bf,
                      const unsigned short* __restrict__ sW1T_bf,
                      const float* __restrict__ dsil,
                      unsigned short* __restrict__ dh1p_bf) {
    const int blk = blockIdx.x, j = threadIdx.x;
    const int b = blk / 12;
    const int wid = j >> 6, L = j & 63;
    const int w = (blk % 12) * 4 + wid;
    const int mp = w & 1, np = w >> 1;
    const int lrow = L & 15, kq = (L >> 4) * 8;
    const unsigned short* A0 = dp_bf + (size_t)(b * TT + mp * 32 + lrow) * CC;
    const unsigned short* A1 = A0 + 16 * CC;
    const int n0 = (2 * np) * 16 + lrow;
    const unsigned short* B0 = sW1T_bf + (size_t)(b * HH + n0) * CC;
    const unsigned short* B1 = B0 + 16 * CC;
    f32x4 acc00 = {0,0,0,0}, acc01 = {0,0,0,0}, acc10 = {0,0,0,0}, acc11 = {0,0,0,0};
    for (int s = 0; s < CC / 32; ++s) {
        int k = s * 32 + kq;
        bf16x8 a0 = ldbf8(A0 + k), a1 = ldbf8(A1 + k);
        bf16x8 b0 = ldbf8(B0 + k), b1 = ldbf8(B1 + k);
        acc00 = mfma16(a0, b0, acc00); acc01 = mfma16(a0, b1, acc01);
        acc10 = mfma16(a1, b0, acc10); acc11 = mfma16(a1, b1, acc11);
    }
    const int quad = L >> 4;
    #pragma unroll
    for (int mi = 0; mi < 2; ++mi) {
        #pragma unroll
        for (int ni = 0; ni < 2; ++ni) {
            f32x4 acc = mi == 0 ? (ni == 0 ? acc00 : acc01) : (ni == 0 ? acc10 : acc11);
            int n = (2 * np + ni) * 16 + lrow;
            #pragma unroll
            for (int r = 0; r < 4; ++r) {
                int t = mp * 32 + mi * 16 + quad * 4 + r;
                size_t idx = (size_t)(b * TT + t) * HH + n;
                dh1p_bf[idx] = f2bf(acc[r] * dsil[idx]);
            }
        }
    }
}

// ---------------- K5: epilogue ----------------
//  [0,288):   nW1[b,c,h] = dfac*sW1 - sum_t (ct*dp)[t,c]*h1[t,h]   (32c x 64h tiles)
//  [288,576): nW0[b,h,c] = dfac*sW0 - sum_t (ct*dh1p)[t,h]*k[t,c]  (32h x 64c tiles)
//  [576,624): out GEMV (16 outputs/block, 16-way K-split, bf16 Wo)
//  [624,626): nb1, nb0
__global__ void k_epi(const unsigned short* __restrict__ dp_bf,
                      const unsigned short* __restrict__ h1_bf,
                      const unsigned short* __restrict__ dh1p_bf,
                      const unsigned short* __restrict__ kb_bf,
                      const float* __restrict__ pred,
                      const float* __restrict__ sW0, const float* __restrict__ sb0,
                      const float* __restrict__ sW1, const float* __restrict__ sb1,
                      const unsigned short* __restrict__ Wo_bf, const float* __restrict__ bo,
                      float* __restrict__ out, Coefs cf) {
    __shared__ float a_t[TT][32];
    __shared__ float e_t[TT][64];
    __shared__ float vecs[CC];
    __shared__ float part[16][17];
    const int blk = blockIdx.x, j = threadIdx.x;

    if (blk < 288) {                       // nW1
        const int b = blk / 144, rem = blk % 144;
        const int c0 = (rem / 12) * 32, h0 = (rem % 12) * 64;
        for (int i = j; i < TT * 32; i += 256) {
            int t = i >> 5, c = i & 31;
            a_t[t][c] = cf.ct[t] * bf2f(dp_bf[((size_t)(b * TT + t)) * CC + c0 + c]);
        }
        for (int i = j; i < TT * 64; i += 256) {
            int t = i >> 6, h = i & 63;
            e_t[t][h] = bf2f(h1_bf[((size_t)(b * TT + t)) * HH + h0 + h]);
        }
        __syncthreads();
        const int ci = j & 31, hb = (j >> 5) * 8;
        float acc[8] = {0, 0, 0, 0, 0, 0, 0, 0};
        for (int t = 0; t < TT; ++t) {
            float av = a_t[t][ci];
            #pragma unroll
            for (int m = 0; m < 8; ++m) acc[m] += av * e_t[t][hb + m];
        }
        const size_t idx = ((size_t)b * CC + c0 + ci) * HH + h0 + hb;
        const float4* w4 = (const float4*)(sW1 + idx);
        float4 wa = w4[0], wb = w4[1];
        float4 o0, o1;
        o0.x = cf.dfac * wa.x - acc[0]; o0.y = cf.dfac * wa.y - acc[1];
        o0.z = cf.dfac * wa.z - acc[2]; o0.w = cf.dfac * wa.w - acc[3];
        o1.x = cf.dfac * wb.x - acc[4]; o1.y = cf.dfac * wb.y - acc[5];
        o1.z = cf.dfac * wb.z - acc[6]; o1.w = cf.dfac * wb.w - acc[7];
        *(float4*)(out + O_NW1 + idx) = o0;
        *(float4*)(out + O_NW1 + idx + 4) = o1;
    } else if (blk < 576) {                // nW0
        const int bk2 = blk - 288;
        const int b = bk2 / 144, rem = bk2 % 144;
        const int h0 = (rem / 6) * 32, c0 = (rem % 6) * 64;
        for (int i = j; i < TT * 32; i += 256) {
            int t = i >> 5, h = i & 31;
            a_t[t][h] = cf.ct[t] * bf2f(dh1p_bf[((size_t)(b * TT + t)) * HH + h0 + h]);
        }
        for (int i = j; i < TT * 64; i += 256) {
            int t = i >> 6, c = i & 63;
            e_t[t][c] = bf2f(kb_bf[((size_t)(b * TT + t)) * CC + c0 + c]);
        }
        __syncthreads();
        const int hi = j & 31, cb = (j >> 5) * 8;
        float acc[8] = {0, 0, 0, 0, 0, 0, 0, 0};
        for (int t = 0; t < TT; ++t) {
            float av = a_t[t][hi];
            #pragma unroll
            for (int m = 0; m < 8; ++m) acc[m] += av * e_t[t][cb + m];
        }
        const size_t idx = ((size_t)b * HH + h0 + hi) * CC + c0 + cb;
        const float4* w4 = (const float4*)(sW0 + idx);
        float4 wa = w4[0], wb = w4[1];
        float4 o0, o1;
        o0.x = cf.dfac * wa.x - acc[0]; o0.y = cf.dfac * wa.y - acc[1];
        o0.z = cf.dfac * wa.z - acc[2]; o0.w = cf.dfac * wa.w - acc[3];
        o1.x = cf.dfac * wb.x - acc[4]; o1.y = cf.dfac * wb.y - acc[5];
        o1.z = cf.dfac * wb.z - acc[6]; o1.w = cf.dfac * wb.w - acc[7];
        *(float4*)(out + O_NW0 + idx) = o0;
        *(float4*)(out + O_NW0 + idx + 4) = o1;
    } else if (blk < 624) {                // out = pred@Wo^T + bo
        const int rb = blk - 576;
        const int b = rb / 24, nt = rb % 24;
        if (j < CC / 4) ((float4*)vecs)[j] = ((const float4*)(pred + b * CC))[j];
        __syncthreads();
        const int nl = j & 15, ks = j >> 4;
        const int n = nt * 16 + nl;
        const unsigned short* wr = Wo_bf + (size_t)n * CC + ks * 24;
        float s = 0.f;
        for (int i = 0; i < 3; ++i) {
            bf16x8 wv8 = ldbf8(wr + i * 8);
            #pragma unroll
            for (int e = 0; e < 8; ++e)
                s += bf2f((unsigned short)wv8[e]) * vecs[ks * 24 + i * 8 + e];
        }
        part[ks][nl] = s;
        __syncthreads();
        if (j < 16) {
            int n2 = nt * 16 + j;
            float acc = bo[n2];
            #pragma unroll
            for (int kk = 0; kk < 16; ++kk) acc += part[kk][j];
            out[O_OUT + b * CC + n2] = acc;
        }
    } else {                               // nb1, nb0
        const int b = blk - 624;
        for (int c = j; c < CC; c += 256) {
            float acc = 0.f;
            for (int t = 0; t < TT; ++t)
                acc += cf.ct[t] * bf2f(dp_bf[((size_t)(b * TT + t)) * CC + c]);
            out[O_NB1 + b * CC + c] = cf.dfac * sb1[b * CC + c] - acc;
        }
        for (int h = j; h < HH; h += 256) {
            float acc = 0.f;
            for (int t = 0; t < TT; ++t)
                acc += cf.ct[t] * bf2f(dh1p_bf[((size_t)(b * TT + t)) * HH + h]);
            out[O_NB0 + b * HH + h] = cf.dfac * sb0[b * HH + h] - acc;
        }
    }
}

extern "C" void kernel_launch(void* const* d_in, const int* in_sizes, int n_in,
                              void* d_out, int out_size, void* d_ws, size_t ws_size,
                              hipStream_t stream) {
    const float* x   = (const float*)d_in[0];
    const float* Wq  = (const float*)d_in[1];
    const float* bq  = (const float*)d_in[2];
    const float* Wk  = (const float*)d_in[3];
    const float* bk  = (const float*)d_in[4];
    const float* Wv  = (const float*)d_in[5];
    const float* bv  = (const float*)d_in[6];
    const float* Wo  = (const float*)d_in[7];
    const float* bo  = (const float*)d_in[8];
    const float* iq  = (const float*)d_in[9];
    const float* sW0 = (const float*)d_in[10];
    const float* sb0 = (const float*)d_in[11];
    const float* sW1 = (const float*)d_in[12];
    const float* sb1 = (const float*)d_in[13];

    // fp32 workspace
    float* fw = (float*)d_ws;
    float* qb   = fw;                 // 384
    float* hret = qb + 384;           // 1536
    float* pred = hret + 1536;        // 768
    float* vb   = pred + 768;         // 49152
    float* dsil = vb + 49152;         // 98304
    // bf16 workspace (16B-aligned: all fp32 counts divisible by 4)
    unsigned short* us = (unsigned short*)(dsil + 98304);
    unsigned short* x_bf    = us;              // 49152
    unsigned short* kb_bf   = x_bf + 49152;    // 49152
    unsigned short* h1_bf   = kb_bf + 49152;   // 98304
    unsigned short* dp_bf   = h1_bf + 98304;   // 49152
    unsigned short* dh1p_bf = dp_bf + 49152;   // 98304
    unsigned short* Wq_bf   = dh1p_bf + 98304; // 147456
    unsigned short* Wk_bf   = Wq_bf + 147456;
    unsigned short* Wv_bf   = Wk_bf + 147456;
    unsigned short* Wo_bf   = Wv_bf + 147456;
    unsigned short* sW0_bf  = Wo_bf + 147456;  // 589824
    unsigned short* sW1_bf  = sW0_bf + 589824; // 589824
    unsigned short* sW1T_bf = sW1_bf + 589824; // 589824  (~6.0 MB total)

    // Closed-form scan coefficients (exact: the clipped seed gate cancels).
    Coefs cf;
    const double mom = 0.9, decay = 1.0 - 0.001, lr = 0.01;
    for (int s = 0; s < TT; ++s) {
        double sum = 0.0;
        for (int t = s; t < TT; ++t) sum += pow(decay, (double)(TT - 1 - t)) * pow(mom, (double)(t - s));
        cf.ct[s] = (float)(lr * (1.0 - mom) * sum);
    }
    cf.dfac = (float)pow(decay, (double)TT);

    k_conv<<<dim3(1776 + 576), dim3(256), 0, stream>>>(x, Wq, Wk, Wv, Wo, sW0, sW1,
        x_bf, Wq_bf, Wk_bf, Wv_bf, Wo_bf, sW0_bf, sW1_bf, sW1T_bf);
    k_qkv<<<dim3(48), dim3(256), 0, stream>>>(x_bf, Wk_bf, bk, Wv_bf, bv, Wq_bf, bq, iq,
                                              kb_bf, vb, qb);
    k_h1 <<<dim3(120), dim3(256), 0, stream>>>(kb_bf, qb, sW0_bf, sb0, h1_bf, dsil, hret);
    k_p  <<<dim3(60), dim3(256), 0, stream>>>(h1_bf, hret, vb, sW1_bf, sb1, dp_bf, pred);
    k_dh1<<<dim3(24), dim3(256), 0, stream>>>(dp_bf, sW1T_bf, dsil, dh1p_bf);
    k_epi<<<dim3(626), dim3(256), 0, stream>>>(dp_bf, h1_bf, dh1p_bf, kb_bf, pred,
                                               sW0, sb0, sW1, sb1, Wo_bf, bo,
                                               (float*)d_out, cf);
}